// Round 1
// baseline (1647.101 us; speedup 1.0000x reference)
//
#include <hip/hip_runtime.h>

// Problem constants
#define BATCH   32
#define CPD     64
#define TSTEPS  1024
#define IN_DIM  256
#define HID     512
#define WIN     1024

typedef _Float16 half2_t __attribute__((ext_vector_type(2)));
typedef _Float16 f16x8   __attribute__((ext_vector_type(8)));
typedef float    f32x4   __attribute__((ext_vector_type(4)));

#define TAG_SALT 0x5A5A0000u

__device__ __forceinline__ float tanh_fast(float x) {
    // tanh(x) = 1 - 2/(e^{2x}+1); exact at +-inf, ~1e-7 abs err in range
    float e = __expf(2.0f * x);
    return 1.0f - 2.0f / (e + 1.0f);
}

// ---------------- A1: M_t[h][c] = sum_i proj[c][i] * W_ih[h][i] ----------------
__global__ __launch_bounds__(512) void k_a1(const float* __restrict__ proj,
                                            const float* __restrict__ W_ih,
                                            float* __restrict__ M_t) {
    __shared__ float p[IN_DIM];
    int c = blockIdx.x;                       // 64 blocks
    if (threadIdx.x < IN_DIM) p[threadIdx.x] = proj[c * IN_DIM + threadIdx.x];
    __syncthreads();
    int h = threadIdx.x;                      // 512 threads
    const float4* wr = (const float4*)(W_ih + (size_t)h * IN_DIM);
    float acc = 0.f;
#pragma unroll
    for (int i = 0; i < IN_DIM / 4; ++i) {
        float4 v = wr[i];
        acc += v.x * p[4*i] + v.y * p[4*i+1] + v.z * p[4*i+2] + v.w * p[4*i+3];
    }
    M_t[(size_t)h * CPD + c] = acc;           // [512][64]
}

// ---------------- C0: convert W_out f32 -> f16 ----------------
__global__ __launch_bounds__(256) void k_cvt(const float* __restrict__ src,
                                             _Float16* __restrict__ dst) {
    int i = (blockIdx.x * 256 + threadIdx.x) * 4;   // 512 blocks covers 524288
    float4 v = *(const float4*)(src + i);
    dst[i+0] = (_Float16)v.x; dst[i+1] = (_Float16)v.y;
    dst[i+2] = (_Float16)v.z; dst[i+3] = (_Float16)v.w;
}

// ---------------- A2: xw[b][t][h] = sum_c control[b][c][t] * M_t[h][c] ----------------
__global__ __launch_bounds__(512) void k_a2(const float* __restrict__ control,
                                            const float* __restrict__ M_t,
                                            float* __restrict__ xw) {
    __shared__ float ctl[CPD][68];            // padded, 16B-aligned rows
    int b  = blockIdx.x >> 4;                 // 32 batches
    int t0 = (blockIdx.x & 15) * 64;          // 16 t-blocks of 64
    int tid = threadIdx.x;                    // 512 threads

    // stage control tile (64 c x 64 t), coalesced float4 along t
    const float* gb = control + (size_t)b * CPD * TSTEPS + t0;
#pragma unroll
    for (int i = 0; i < 2; ++i) {
        int flat4 = tid * 2 + i;              // 0..1023 quads
        int c = flat4 >> 4, t4 = (flat4 & 15) * 4;
        float4 v = *(const float4*)(gb + (size_t)c * TSTEPS + t4);
        *(float4*)&ctl[c][t4] = v;
    }
    // M row into regs
    int h = tid;
    float mrow[CPD];
    const float4* mp = (const float4*)(M_t + (size_t)h * CPD);
#pragma unroll
    for (int i = 0; i < CPD / 4; ++i) {
        float4 v = mp[i];
        mrow[4*i] = v.x; mrow[4*i+1] = v.y; mrow[4*i+2] = v.z; mrow[4*i+3] = v.w;
    }
    __syncthreads();

    float* xo = xw + ((size_t)b * TSTEPS + t0) * HID + h;
#pragma unroll
    for (int half = 0; half < 2; ++half) {
        float acc[32];
#pragma unroll
        for (int q = 0; q < 32; ++q) acc[q] = 0.f;
#pragma unroll
        for (int c = 0; c < CPD; ++c) {
            float m = mrow[c];
#pragma unroll
            for (int q = 0; q < 8; ++q) {
                float4 v = *(const float4*)&ctl[c][half * 32 + q * 4];  // broadcast read
                acc[q*4+0] += v.x * m; acc[q*4+1] += v.y * m;
                acc[q*4+2] += v.z * m; acc[q*4+3] += v.w * m;
            }
        }
#pragma unroll
        for (int tt = 0; tt < 32; ++tt)
            xo[(size_t)(half * 32 + tt) * HID] = acc[tt];
    }
}

// ---------------- B: sequential recurrence ----------------
// 256 wgs: batch = bid&31, chunk = bid>>5 (8 chunks of 64 rows). W_hh slice in VGPRs (f16).
// h exchanged via tagged 64-bit words, double-buffered by parity. No fences needed:
// tag+value share one atomic word.
__device__ __forceinline__ void publish(unsigned long long* p, unsigned int tag, float v) {
    unsigned long long pk = ((unsigned long long)tag << 32) | (unsigned long long)__float_as_uint(v);
    __hip_atomic_store(p, pk, __ATOMIC_RELAXED, __HIP_MEMORY_SCOPE_AGENT);
}
__device__ __forceinline__ float poll(unsigned long long* p, unsigned int want) {
    unsigned long long v;
    do {
        v = __hip_atomic_load(p, __ATOMIC_RELAXED, __HIP_MEMORY_SCOPE_AGENT);
    } while ((unsigned int)(v >> 32) != want);
    return __uint_as_float((unsigned int)v);
}

__global__ __launch_bounds__(256, 1) void k_scan(const float* __restrict__ W_hh,
                                                 const float* __restrict__ xw,
                                                 unsigned long long* __restrict__ hbuf,
                                                 _Float16* __restrict__ hs) {
    int bid = blockIdx.x;
    int b = bid & 31, chunk = bid >> 5;       // same blockIdx%8 within a batch group
    int r0 = chunk * 64;
    int tid = threadIdx.x;
    int l = tid & 63, c = tid >> 6;           // lane -> row, wave -> k-chunk

    // load W slice: row r0+l, k in [c*128, c*128+128) as 64 f16 pairs in VGPRs
    half2_t w[64];
    const float2* wr = (const float2*)(W_hh + (size_t)(r0 + l) * HID + c * 128);
#pragma unroll
    for (int j = 0; j < 64; ++j) {
        float2 f = wr[j];
        half2_t hv = {(_Float16)f.x, (_Float16)f.y};
        w[j] = hv;
    }

    __shared__ half2_t hlds[256];             // full h (512) as f16 pairs
    __shared__ float   part[4][64];

    unsigned long long* hb0 = hbuf + (size_t)b * HID;                 // parity 0
    unsigned long long* hb1 = hbuf + (size_t)BATCH * HID + (size_t)b * HID; // parity 1
    const float* xwb = xw + (size_t)b * TSTEPS * HID;
    _Float16* hsb = hs + (size_t)b * TSTEPS * HID;

    float xw_next = 0.f;
    // step 1: h1 = tanh(xw[0]) (h0 = 0, no communication needed)
    if (tid < 64) {
        int r = r0 + tid;
        float hv = tanh_fast(xwb[r]);
        hsb[r] = (_Float16)hv;
        publish(hb1 + r, TAG_SALT + 1u, hv);
        xw_next = xwb[HID + r];               // prefetch xw[1]
    }

#pragma unroll 1
    for (int t = 2; t <= TSTEPS; ++t) {
        unsigned long long* rdbuf = ((t - 1) & 1) ? hb1 : hb0;
        unsigned long long* wrbuf = (t & 1) ? hb1 : hb0;
        unsigned int want = TAG_SALT + (unsigned int)(t - 1);
        // gather h_{t-1}: 2 elements per thread
        float v0 = poll(rdbuf + 2 * tid, want);
        float v1 = poll(rdbuf + 2 * tid + 1, want);
        half2_t hv = {(_Float16)v0, (_Float16)v1};
        hlds[tid] = hv;
        __syncthreads();

        // partial dot over this wave's 128 k's (4 independent chains)
        const half2_t* hp = hlds + c * 64;
        float a0 = 0.f, a1 = 0.f, a2 = 0.f, a3 = 0.f;
#pragma unroll
        for (int q = 0; q < 16; ++q) {
            half2_t h0 = hp[4*q], h1 = hp[4*q+1], h2 = hp[4*q+2], h3 = hp[4*q+3];
            a0 = __builtin_amdgcn_fdot2(w[4*q+0], h0, a0, false);
            a1 = __builtin_amdgcn_fdot2(w[4*q+1], h1, a1, false);
            a2 = __builtin_amdgcn_fdot2(w[4*q+2], h2, a2, false);
            a3 = __builtin_amdgcn_fdot2(w[4*q+3], h3, a3, false);
        }
        part[c][l] = (a0 + a1) + (a2 + a3);
        __syncthreads();

        if (tid < 64) {
            int r = r0 + tid;
            float s = part[0][tid] + part[1][tid] + part[2][tid] + part[3][tid] + xw_next;
            float hv2 = tanh_fast(s);
            hsb[(size_t)(t - 1) * HID + r] = (_Float16)hv2;
            publish(wrbuf + r, TAG_SALT + (unsigned int)t, hv2);
            if (t < TSTEPS) xw_next = xwb[(size_t)t * HID + r]; // prefetch next
        }
    }
}

// ---------------- C: out[row][w] = sin( sum_h hs[row][h] * Wout[w][h] ) ----------------
// 128x128 tile, BK=32, 4 waves in 2x2 quadrants, f16 MFMA 16x16x32.
__global__ void k_outgemm(const _Float16* __restrict__ hs,
                          const _Float16* __restrict__ Wo,
                          float* __restrict__ out) {
    __shared__ _Float16 Ap[128][40];          // +8 pad: conflict-free frag reads
    __shared__ _Float16 Bp[128][40];
    int tid = threadIdx.x;
    int r0 = blockIdx.x * 128;                // 256 M-tiles
    int c0 = blockIdx.y * 128;                // 8 N-tiles
    int wid = tid >> 6, l = tid & 63;
    int wr = (wid >> 1) * 64, wc = (wid & 1) * 64;
    int lrow = tid & 127, lhalf = (tid >> 7) * 16;   // staging assignment
    int fr = l & 15, kg = (l >> 4) * 8;

    f32x4 acc[4][4];
#pragma unroll
    for (int m = 0; m < 4; ++m)
#pragma unroll
        for (int n = 0; n < 4; ++n) acc[m][n] = (f32x4){0.f, 0.f, 0.f, 0.f};

    for (int k0 = 0; k0 < HID; k0 += 32) {
        const uint4* ga = (const uint4*)(hs + (size_t)(r0 + lrow) * HID + k0 + lhalf);
        uint4 a0 = ga[0], a1 = ga[1];
        const uint4* gbp = (const uint4*)(Wo + (size_t)(c0 + lrow) * HID + k0 + lhalf);
        uint4 b0 = gbp[0], b1 = gbp[1];
        __syncthreads();                      // prev-iter reads done
        *(uint4*)&Ap[lrow][lhalf] = a0; *(uint4*)&Ap[lrow][lhalf + 8] = a1;
        *(uint4*)&Bp[lrow][lhalf] = b0; *(uint4*)&Bp[lrow][lhalf + 8] = b1;
        __syncthreads();

        f16x8 af[4], bf[4];
#pragma unroll
        for (int m = 0; m < 4; ++m) af[m] = *(const f16x8*)&Ap[wr + m * 16 + fr][kg];
#pragma unroll
        for (int n = 0; n < 4; ++n) bf[n] = *(const f16x8*)&Bp[wc + n * 16 + fr][kg];
#pragma unroll
        for (int m = 0; m < 4; ++m)
#pragma unroll
            for (int n = 0; n < 4; ++n)
                acc[m][n] = __builtin_amdgcn_mfma_f32_16x16x32_f16(af[m], bf[n], acc[m][n], 0, 0, 0);
    }

    int fq = l >> 4;
#pragma unroll
    for (int m = 0; m < 4; ++m)
#pragma unroll
        for (int n = 0; n < 4; ++n)
#pragma unroll
            for (int q = 0; q < 4; ++q) {
                int row = r0 + wr + m * 16 + fq * 4 + q;
                int col = c0 + wc + n * 16 + fr;
                out[(size_t)row * WIN + col] = __sinf(acc[m][n][q]);
            }
}

// ---------------- launch ----------------
extern "C" void kernel_launch(void* const* d_in, const int* in_sizes, int n_in,
                              void* d_out, int out_size, void* d_ws, size_t ws_size,
                              hipStream_t stream) {
    const float* control = (const float*)d_in[0];  // (32, 64, 1024)
    const float* proj    = (const float*)d_in[1];  // (64, 256)
    const float* W_ih    = (const float*)d_in[2];  // (512, 256)
    const float* W_hh    = (const float*)d_in[3];  // (512, 512)
    const float* W_out   = (const float*)d_in[4];  // (1024, 512)
    float* out = (float*)d_out;                    // 32 * 1024 * 1024 f32

    // workspace carve
    const size_t XW_B   = (size_t)BATCH * TSTEPS * HID * 4;     // 64 MiB
    const size_t MT_B   = (size_t)HID * CPD * 4;                // 128 KiB
    const size_t HBUF_B = 2ull * BATCH * HID * 8;               // 256 KiB
    const size_t HS_B   = (size_t)BATCH * TSTEPS * HID * 2;     // 32 MiB
    const size_t WO_B   = (size_t)WIN * HID * 2;                // 1 MiB
    if (ws_size < XW_B + MT_B + HBUF_B + HS_B + WO_B) return;

    char* ws = (char*)d_ws;
    float* xw = (float*)ws;                          ws += XW_B;
    float* M_t = (float*)ws;                         ws += MT_B;
    unsigned long long* hbuf = (unsigned long long*)ws; ws += HBUF_B;
    _Float16* hs = (_Float16*)ws;                    ws += HS_B;
    _Float16* Wo = (_Float16*)ws;

    k_a1<<<CPD, 512, 0, stream>>>(proj, W_ih, M_t);
    k_cvt<<<512, 256, 0, stream>>>(W_out, Wo);
    k_a2<<<BATCH * 16, 512, 0, stream>>>(control, M_t, xw);
    k_scan<<<256, 256, 0, stream>>>(W_hh, xw, hbuf, hs);
    k_outgemm<<<dim3(256, 8), 256, 0, stream>>>(hs, Wo, out);
}